// Round 9
// baseline (270.704 us; speedup 1.0000x reference)
//
#include <hip/hip_runtime.h>
#include <hip/hip_bf16.h>
#include <math.h>

#define B_ 2
#define L_ 1024
#define D_ 1024
#define H_ 16

typedef short short8 __attribute__((ext_vector_type(8)));
typedef short short4v __attribute__((ext_vector_type(4)));
typedef float f32x4  __attribute__((ext_vector_type(4)));

__device__ __forceinline__ short f2bf(float f) {
  unsigned u = __float_as_uint(f);
  u += 0x7fff + ((u >> 16) & 1);          // RNE
  return (short)(u >> 16);
}
__device__ __forceinline__ float bf2f(short s) {
  return __uint_as_float(((unsigned)(unsigned short)s) << 16);
}
// XOR-swizzled LDS index (shorts) for [rows][64] bf16 tiles (16B slots).
__device__ __forceinline__ int swz(int row, int slot) {
  return row * 64 + (((slot ^ row) & 7) << 3);
}
// P-tile XOR key (wave-private P buffer bank spread)
__device__ __forceinline__ int pkey(int row) {
  return (row & 7) ^ ((row & 8) >> 2);
}
// global -> LDS direct (16B/lane; LDS dest = wave-uniform base + lane*16)
__device__ __forceinline__ void glds16(const void* g, void* l) {
  __builtin_amdgcn_global_load_lds((const __attribute__((address_space(1))) void*)g,
                                   (__attribute__((address_space(3))) void*)l, 16, 0, 0);
}

// ---------------------------------------------------------------------------
// prep: (a) cast E,Ev,R -> bf16 contiguous; (b) transpose+cast 5 weights.
// ---------------------------------------------------------------------------
__global__ __launch_bounds__(256) void prep(
    const float* __restrict__ E, const float* __restrict__ Ev,
    const float* __restrict__ R,
    const float* __restrict__ W0, const float* __restrict__ W1,
    const float* __restrict__ W2, const float* __restrict__ W3,
    const float* __restrict__ W4,
    short* __restrict__ act, short* __restrict__ Wt) {
  __shared__ short t[64][65];
  const int tid = threadIdx.x;
  int bid = blockIdx.x;
  if (bid < 2560) {
    size_t i8 = ((size_t)bid * 256 + tid) * 8;
    const float* src; size_t off;
    if (i8 < 2097152)      { src = E;  off = i8; }
    else if (i8 < 4194304) { src = Ev; off = i8 - 2097152; }
    else                   { src = R;  off = i8 - 4194304; }
    float4 a = *(const float4*)&src[off];
    float4 b = *(const float4*)&src[off + 4];
    short8 v;
    v[0] = f2bf(a.x); v[1] = f2bf(a.y); v[2] = f2bf(a.z); v[3] = f2bf(a.w);
    v[4] = f2bf(b.x); v[5] = f2bf(b.y); v[6] = f2bf(b.z); v[7] = f2bf(b.w);
    *(short8*)&act[i8] = v;
    return;
  }
  bid -= 2560;
  const int z = bid >> 8, rem = bid & 255;
  const int by = rem >> 4, bx = rem & 15;
  const float* W = (z == 0) ? W0 : (z == 1) ? W1 : (z == 2) ? W2 : (z == 3) ? W3 : W4;
  short* Wtz = Wt + (size_t)z * D_ * D_;
  const int r0 = by * 64, c0 = bx * 64;
  #pragma unroll
  for (int i = 0; i < 4; ++i) {
    int idx = tid + i * 256;
    int r = idx >> 4, c4 = (idx & 15) * 4;
    float4 v = *(const float4*)&W[(size_t)(r0 + r) * D_ + c0 + c4];
    t[c4 + 0][r] = f2bf(v.x); t[c4 + 1][r] = f2bf(v.y);
    t[c4 + 2][r] = f2bf(v.z); t[c4 + 3][r] = f2bf(v.w);
  }
  __syncthreads();
  #pragma unroll
  for (int i = 0; i < 2; ++i) {
    int idx = tid + i * 256;
    int rr = idx >> 3, cc = (idx & 7) * 8;
    short8 o;
    #pragma unroll
    for (int e = 0; e < 8; ++e) o[e] = t[rr][cc + e];
    *(short8*)&Wtz[(size_t)(c0 + rr) * D_ + r0 + cc] = o;
  }
}

// ---------------------------------------------------------------------------
// Double-buffered bf16 MFMA GEMM (R7 config: NF=2, 32KB LDS, 5 blocks/CU).
// C = A[M,1024] @ Bt[1024,1024]^T. Tile 64x64, BK=64, 4 waves. STAGE(t+1)
// before COMPUTE(t); 1 barrier/K-step. OUT: 0 bf16, 1 f32, 2 bf16 per-head
// transposed vt[((b*16+h)*64+d)*1024 + j].
// ---------------------------------------------------------------------------
template<int NF, int OUT>
__device__ __forceinline__ void mm_db(const short* __restrict__ A,
                                      const short* __restrict__ Bt,
                                      void* __restrict__ Cp,
                                      int bx, int by) {
  __shared__ short As0[4096], As1[4096];
  __shared__ short Bs0[NF * 2048], Bs1[NF * 2048];
  const int tid = threadIdx.x;
  const int l = tid & 63, w = tid >> 6;
  const int row0 = by * 64, col0 = bx * (NF * 32);
  const int wm = (w >> 1) * 32, wn = (w & 1) * (NF * 16);
  const int lr = l >> 3;
  const int lc = ((l & 7) ^ lr) * 8;     // inverse-swizzled source slot
  const f32x4 fz = {0.f, 0.f, 0.f, 0.f};

  f32x4 acc[2][NF];
  #pragma unroll
  for (int i = 0; i < 2; ++i)
    #pragma unroll
    for (int j = 0; j < NF; ++j) acc[i][j] = fz;

  auto STAGE = [&](short* AsD, short* BsD, int k0) {
    #pragma unroll
    for (int c = 0; c < 2; ++c) {
      int ch = w * 2 + c;
      glds16(&A[(size_t)(row0 + ch * 8 + lr) * 1024 + k0 + lc], &AsD[ch * 512]);
    }
    #pragma unroll
    for (int c = 0; c < NF; ++c) {
      int ch = w * NF + c;
      glds16(&Bt[(size_t)(col0 + ch * 8 + lr) * 1024 + k0 + lc], &BsD[ch * 512]);
    }
  };
  auto COMP = [&](const short* AsS, const short* BsS) {
    #pragma unroll
    for (int kf = 0; kf < 2; ++kf) {
      const int slot = kf * 4 + (l >> 4);
      short8 a[2], bfr[NF];
      #pragma unroll
      for (int mf = 0; mf < 2; ++mf)
        a[mf] = *(const short8*)&AsS[swz(wm + mf * 16 + (l & 15), slot)];
      #pragma unroll
      for (int nf = 0; nf < NF; ++nf)
        bfr[nf] = *(const short8*)&BsS[swz(wn + nf * 16 + (l & 15), slot)];
      #pragma unroll
      for (int mf = 0; mf < 2; ++mf)
        #pragma unroll
        for (int nf = 0; nf < NF; ++nf)
          acc[mf][nf] = __builtin_amdgcn_mfma_f32_16x16x32_bf16(a[mf], bfr[nf], acc[mf][nf], 0, 0, 0);
    }
  };

  STAGE(As0, Bs0, 0);
  __syncthreads();
  for (int t = 0; t < 16; t += 2) {
    if (t + 1 < 16) STAGE(As1, Bs1, (t + 1) * 64);
    COMP(As0, Bs0);
    __syncthreads();
    if (t + 2 < 16) STAGE(As0, Bs0, (t + 2) * 64);
    COMP(As1, Bs1);
    __syncthreads();
  }

  #pragma unroll
  for (int mf = 0; mf < 2; ++mf)
    #pragma unroll
    for (int nf = 0; nf < NF; ++nf) {
      if (OUT == 2) {
        int tok = row0 + wm + mf * 16 + (l >> 4) * 4;
        int col = col0 + wn + nf * 16 + (l & 15);
        int bb = tok >> 10, j = tok & 1023;
        int h = col >> 6, d = col & 63;
        short4v o;
        #pragma unroll
        for (int r = 0; r < 4; ++r) o[r] = f2bf(acc[mf][nf][r]);
        *(short4v*)&((short*)Cp)[((size_t)((bb * H_ + h) * 64 + d)) * 1024 + j] = o;
      } else {
        #pragma unroll
        for (int r = 0; r < 4; ++r) {
          int row = row0 + wm + mf * 16 + (l >> 4) * 4 + r;
          int col = col0 + wn + nf * 16 + (l & 15);
          if (OUT == 1) ((float*)Cp)[(size_t)row * 1024 + col] = acc[mf][nf][r];
          else          ((short*)Cp)[(size_t)row * 1024 + col] = f2bf(acc[mf][nf][r]);
        }
      }
    }
}

// z=0: q=Eb@Wq ; z=1: k=Evb@Wke ; z=2: vt=(Evb@Wv)^T ; z=3: Qp=Rb@Wkr.
__global__ __launch_bounds__(256) void proj_g(
    const short* __restrict__ Eb, const short* __restrict__ Evb,
    const short* __restrict__ Rb, const short* __restrict__ Wt,
    short* __restrict__ qb, short* __restrict__ kb,
    short* __restrict__ vt, short* __restrict__ Qpb) {
  const int z = blockIdx.z;
  const size_t MM = (size_t)D_ * D_;
  const short* A; const short* Bt; short* C; int M;
  if (z == 0)      { A = Eb;  Bt = Wt;          C = qb;  M = B_ * L_; }
  else if (z == 1) { A = Evb; Bt = Wt + MM;     C = kb;  M = B_ * L_; }
  else if (z == 2) { A = Evb; Bt = Wt + 3 * MM; C = vt;  M = B_ * L_; }
  else             { A = Rb;  Bt = Wt + 2 * MM; C = Qpb; M = L_;      }
  if ((int)blockIdx.y * 64 >= M) return;
  if (z == 2) mm_db<2, 2>(A, Bt, C, blockIdx.x, blockIdx.y);
  else        mm_db<2, 0>(A, Bt, C, blockIdx.x, blockIdx.y);
}

__global__ __launch_bounds__(256) void out_g(
    const short* __restrict__ Ob, const short* __restrict__ Wot,
    float* __restrict__ proj) {
  mm_db<2, 1>(Ob, Wot, proj, blockIdx.x, blockIdx.y);
}

// ---------------------------------------------------------------------------
// MFMA attention, 8 waves, in-block j-split. Block = 64 q-rows of one (b,h).
// Waves 0-3 (grp 0) process even j-tiles, waves 4-7 (grp 1) odd j-tiles,
// each with private (m,l,O); flash-merge via LDS at the end. K/V^T pair-
// staged dbuf via glds16 (1 barrier/round, stage-before-compute). Window Qp
// per-wave register prefetch. Positional diagonal shift via in-register
// __shfl remap (shift uniform per 16-lane row group). Biases folded:
// S = (q+cb).k + (q+pb).Qp[m].
// ---------------------------------------------------------------------------
__global__ __launch_bounds__(512, 4) void attn_s(
    const short* __restrict__ qb, const short* __restrict__ kb,
    const short* __restrict__ vt, const short* __restrict__ Qpb,
    const float* __restrict__ cb, const float* __restrict__ pb,
    short* __restrict__ Ob) {
  __shared__ short k_s[2][2][4096];   // [buf][pairIdx][64x64]
  __shared__ short v_s[2][2][4096];
  __shared__ short p_s[8][1024];      // per-wave P[16][64]

  const int tid = threadIdx.x;
  const int l = tid & 63, w = tid >> 6;   // w 0..7
  const int grp = w >> 2, wl = w & 3;
  const int hl = blockIdx.x & 31;         // (b,h) fastest -> XCD L2 locality
  const int it = blockIdx.x >> 5;         // 0..15
  const int b = hl >> 4, hh = hl & 15;
  const int i0 = it * 64;
  const int i0w = i0 + wl * 16;           // this wave's first q row
  const f32x4 fz = {0.f, 0.f, 0.f, 0.f};

  const int lr = l >> 3;
  const int lc = ((l & 7) ^ lr) * 8;      // inverse-swizzled source slot

  // ---- A-fragments with folded biases ----
  short8 aqc[2], aqp[2];
  {
    const size_t qoff = (size_t)(b * L_ + i0w + (l & 15)) * D_ + hh * 64 + (l >> 4) * 8;
    #pragma unroll
    for (int kf = 0; kf < 2; ++kf) {
      short8 qv = *(const short8*)&qb[qoff + kf * 32];
      const float* cbp = &cb[hh * 64 + kf * 32 + (l >> 4) * 8];
      const float* pbp = &pb[hh * 64 + kf * 32 + (l >> 4) * 8];
      #pragma unroll
      for (int e = 0; e < 8; ++e) {
        float q = bf2f(qv[e]);
        aqc[kf][e] = f2bf(q + cbp[e]);
        aqp[kf][e] = f2bf(q + pbp[e]);
      }
    }
  }

  const short* kbase  = &kb[(size_t)(b * L_) * D_ + hh * 64];
  const short* vtbase = &vt[(size_t)((b * H_ + hh) * 64) * 1024];
  const short* wbase  = &Qpb[hh * 64 + (l >> 4) * 8];

  // pair staging: wave w stages chunk w (8 rows) of each {k,v}x{tile0,tile1}
  auto STAGE = [&](int buf, int rnd) {
    #pragma unroll
    for (int tp = 0; tp < 2; ++tp) {
      const int j0 = (2 * rnd + tp) * 64;
      glds16(&kbase[(size_t)(j0 + w * 8 + lr) * D_ + lc], &k_s[buf][tp][w * 512]);
      glds16(&vtbase[(size_t)(w * 8 + lr) * 1024 + j0 + lc], &v_s[buf][tp][w * 512]);
    }
  };

  // window prefetch (per-wave, direct global -> regs, one my-tile ahead)
  short8 bw[2][5];
  auto LW = [&](int jt) {
    const int mb = L_ - 16 - (i0w - jt * 64);
    #pragma unroll
    for (int kf = 0; kf < 2; ++kf)
      #pragma unroll
      for (int u = 0; u < 5; ++u) {
        int m = mb + u * 16 + (l & 15);
        m = (m < L_) ? m : (L_ - 1);      // clamped rows masked in remap
        bw[kf][u] = *(const short8*)&wbase[(size_t)m * D_ + kf * 32];
      }
  };

  STAGE(0, 0);
  if (i0w - grp * 64 >= -15) LW(grp);     // first my-tile (if positional)
  __syncthreads();

  float mrow[4], lrow[4];
  f32x4 oacc[4];
  #pragma unroll
  for (int r = 0; r < 4; ++r) { mrow[r] = -3.0e38f; lrow[r] = 0.f; }
  #pragma unroll
  for (int nf = 0; nf < 4; ++nf) oacc[nf] = fz;

  for (int rnd = 0; rnd < 8; ++rnd) {
    const int jt = 2 * rnd + grp;
    const int dth = i0w - jt * 64;        // j<=i  <=>  rj <= ris + dth
    const bool pos = (dth >= -15);
    const short* kS = k_s[rnd & 1][grp];
    const short* vS = v_s[rnd & 1][grp];

    if (rnd < 7) STAGE((rnd + 1) & 1, rnd + 1);   // flies under compute

    // ---- QK^T ----
    f32x4 sac[4];
    #pragma unroll
    for (int nf = 0; nf < 4; ++nf) sac[nf] = fz;
    __builtin_amdgcn_s_setprio(1);
    #pragma unroll
    for (int kf = 0; kf < 2; ++kf) {
      const int slot = kf * 4 + (l >> 4);
      #pragma unroll
      for (int nf = 0; nf < 4; ++nf) {
        short8 bk = *(const short8*)&kS[swz(nf * 16 + (l & 15), slot)];
        sac[nf] = __builtin_amdgcn_mfma_f32_16x16x32_bf16(aqc[kf], bk, sac[nf], 0, 0, 0);
      }
    }
    __builtin_amdgcn_s_setprio(0);

    // ---- positional GEMM from prefetched bw ----
    f32x4 pacc[5];
    if (pos) {
      #pragma unroll
      for (int u = 0; u < 5; ++u) pacc[u] = fz;
      __builtin_amdgcn_s_setprio(1);
      #pragma unroll
      for (int kf = 0; kf < 2; ++kf)
        #pragma unroll
        for (int u = 0; u < 5; ++u)
          pacc[u] = __builtin_amdgcn_mfma_f32_16x16x32_bf16(aqp[kf], bw[kf][u], pacc[u], 0, 0, 0);
      __builtin_amdgcn_s_setprio(0);
    }

    // prefetch next my-tile's window (bw dead after pos MFMAs above)
    if (rnd < 7 && dth - 128 >= -15) LW(jt + 2);

    if (pos) {
      // in-register diagonal remap: S[ris][rj] += pacc value at window col
      // cw = (15-ris) + rj.  Shift (15-ris) uniform per 16-lane row group.
      const int c = l & 15;
      #pragma unroll
      for (int r = 0; r < 4; ++r) {
        const int ris = (l >> 4) * 4 + r;
        const int t = (15 - ris) + c;            // 0..30
        const int sl = (l & 48) | (t & 15);      // absolute source lane
        const bool hi = t >= 16;
        float shf[5];
        #pragma unroll
        for (int u = 0; u < 5; ++u) shf[u] = __shfl(pacc[u][r], sl, 64);
        #pragma unroll
        for (int nf = 0; nf < 4; ++nf) {
          int rj = nf * 16 + c;
          if (rj <= ris + dth) sac[nf][r] += hi ? shf[nf + 1] : shf[nf];
        }
      }
    }

    // ---- online softmax (16-lane row groups) ----
    #pragma unroll
    for (int r = 0; r < 4; ++r) {
      float mx = fmaxf(fmaxf(sac[0][r], sac[1][r]), fmaxf(sac[2][r], sac[3][r]));
      #pragma unroll
      for (int off = 1; off < 16; off <<= 1)
        mx = fmaxf(mx, __shfl_xor(mx, off, 64));
      float mn = fmaxf(mrow[r], mx);
      float sc = __expf(mrow[r] - mn);
      mrow[r] = mn;
      float ls = 0.f;
      #pragma unroll
      for (int nf = 0; nf < 4; ++nf) {
        float p = __expf(sac[nf][r] - mn);
        sac[nf][r] = p;
        ls += p;
      }
      #pragma unroll
      for (int off = 1; off < 16; off <<= 1)
        ls += __shfl_xor(ls, off, 64);
      lrow[r] = lrow[r] * sc + ls;
      #pragma unroll
      for (int nf = 0; nf < 4; ++nf) oacc[nf][r] *= sc;
    }

    // ---- P -> bf16, wave-private LDS ----
    #pragma unroll
    for (int nf = 0; nf < 4; ++nf)
      #pragma unroll
      for (int r = 0; r < 4; ++r) {
        int row = (l >> 4) * 4 + r;
        int col = nf * 16 + (l & 15);
        p_s[w][row * 64 + (((col >> 3) ^ pkey(row)) << 3) + (col & 7)] = f2bf(sac[nf][r]);
      }

    // ---- PV from staged V^T ----
    __builtin_amdgcn_s_setprio(1);
    #pragma unroll
    for (int kf = 0; kf < 2; ++kf) {
      int prow = l & 15;
      short8 ap = *(const short8*)&p_s[w][prow * 64 + (((kf * 4 + (l >> 4)) ^ pkey(prow)) << 3)];
      #pragma unroll
      for (int nf = 0; nf < 4; ++nf) {
        short8 bv = *(const short8*)&vS[swz(nf * 16 + (l & 15), kf * 4 + (l >> 4))];
        oacc[nf] = __builtin_amdgcn_mfma_f32_16x16x32_bf16(ap, bv, oacc[nf], 0, 0, 0);
      }
    }
    __builtin_amdgcn_s_setprio(0);

    __syncthreads();   // next-round stage complete; buffers rotate
  }

  // ---- merge the two j-streams (flash combine) via LDS ----
  float* mO = (float*)&k_s[0][0][0];      // [4 waves][16 rows][64 cols] f32
  float* mM = (float*)&v_s[0][0][0];      // [4][16]
  float* mL = mM + 64;
  if (grp == 1) {
    #pragma unroll
    for (int r = 0; r < 4; ++r) {
      int ris = (l >> 4) * 4 + r;
      #pragma unroll
      for (int nf = 0; nf < 4; ++nf)
        mO[(wl * 16 + ris) * 64 + nf * 16 + (l & 15)] = oacc[nf][r];
      if ((l & 15) == 0) { mM[wl * 16 + ris] = mrow[r]; mL[wl * 16 + ris] = lrow[r]; }
    }
  }
  __syncthreads();
  if (grp == 0) {
    #pragma unroll
    for (int r = 0; r < 4; ++r) {
      int ris = (l >> 4) * 4 + r;
      float mB = mM[wl * 16 + ris], lB = mL[wl * 16 + ris];
      float m = fmaxf(mrow[r], mB);
      float eA = __expf(mrow[r] - m), eB = __expf(mB - m);
      float inv = 1.f / (lrow[r] * eA + lB * eB);
      int row = i0w + ris;
      #pragma unroll
      for (int nf = 0; nf < 4; ++nf) {
        float vB = mO[(wl * 16 + ris) * 64 + nf * 16 + (l & 15)];
        int col = hh * 64 + nf * 16 + (l & 15);
        Ob[(size_t)(b * L_ + row) * D_ + col] = f2bf((oacc[nf][r] * eA + vB * eB) * inv);
      }
    }
  }
}

// ---------------------------------------------------------------------------
// res = Ev + proj + Wo_b; LayerNorm * g + b. One block per row.
// ---------------------------------------------------------------------------
__global__ __launch_bounds__(256) void ln_kernel(
    const float* __restrict__ Ev, const float* __restrict__ proj,
    const float* __restrict__ Wo_b, const float* __restrict__ g,
    const float* __restrict__ beta, float* __restrict__ out) {
  const int row = blockIdx.x;
  __shared__ float red[8];
  const int tid = threadIdx.x;
  const int d = tid * 4;

  float4 e  = *(const float4*)&Ev[(size_t)row * D_ + d];
  float4 p  = *(const float4*)&proj[(size_t)row * D_ + d];
  float4 wb = *(const float4*)&Wo_b[d];
  float4 rr = { e.x + p.x + wb.x, e.y + p.y + wb.y,
                e.z + p.z + wb.z, e.w + p.w + wb.w };
  float sum = rr.x + rr.y + rr.z + rr.w;
  float sq  = rr.x * rr.x + rr.y * rr.y + rr.z * rr.z + rr.w * rr.w;

  #pragma unroll
  for (int off = 1; off < 64; off <<= 1) {
    sum += __shfl_xor(sum, off, 64);
    sq  += __shfl_xor(sq,  off, 64);
  }
  const int wid = tid >> 6;
  if ((tid & 63) == 0) { red[wid * 2] = sum; red[wid * 2 + 1] = sq; }
  __syncthreads();
  sum = red[0] + red[2] + red[4] + red[6];
  sq  = red[1] + red[3] + red[5] + red[7];

  const float mu   = sum * (1.f / (float)D_);
  const float var  = sq * (1.f / (float)D_) - mu * mu;
  const float rstd = rsqrtf(var + 1e-5f);

  float4 gg = *(const float4*)&g[d];
  float4 bb = *(const float4*)&beta[d];
  float4 o = { (rr.x - mu) * rstd * gg.x + bb.x,
               (rr.y - mu) * rstd * gg.y + bb.y,
               (rr.z - mu) * rstd * gg.z + bb.z,
               (rr.w - mu) * rstd * gg.w + bb.w };
  *(float4*)&out[(size_t)row * D_ + d] = o;
}

// ---------------------------------------------------------------------------
extern "C" void kernel_launch(void* const* d_in, const int* in_sizes, int n_in,
                              void* d_out, int out_size, void* d_ws, size_t ws_size,
                              hipStream_t stream) {
  const float* E    = (const float*)d_in[0];
  const float* Ev   = (const float*)d_in[1];
  const float* R    = (const float*)d_in[2];
  const float* Wq   = (const float*)d_in[3];
  const float* Wke  = (const float*)d_in[4];
  const float* Wkr  = (const float*)d_in[5];
  const float* Wv   = (const float*)d_in[6];
  const float* cb   = (const float*)d_in[7];
  const float* pb   = (const float*)d_in[8];
  const float* Wo_w = (const float*)d_in[9];
  const float* Wo_b = (const float*)d_in[10];
  const float* ln_g = (const float*)d_in[11];
  const float* ln_b = (const float*)d_in[12];
  float* out = (float*)d_out;

  // ws (shorts): Eb 2M | Evb 2M | Rb 1M | qb 2M | kb 2M | vt 2M | Qpb 1M |
  // Wt 5M | Ob 2M = 19M shorts = 38MB. proj fp32 overlays Eb+Evb.
  short* ws   = (short*)d_ws;
  short* Eb   = ws;
  short* Evb  = ws + 2097152;
  short* Rb   = ws + 4194304;
  short* qb   = ws + 5242880;
  short* kb   = ws + 7340032;
  short* vt   = ws + 9437184;
  short* Qpb  = ws + 11534336;
  short* Wt   = ws + 12582912;
  short* Ob   = ws + 17825792;
  float* proj = (float*)Eb;

  // 1) prep: cast activations + transpose/cast weights
  prep<<<3840, 256, 0, stream>>>(E, Ev, R, Wq, Wke, Wkr, Wv, Wo_w, Eb, Wt);

  // 2) projections -> bf16 q, k, vt(transposed), Qp  (R7 NF=2 dbuf config)
  proj_g<<<dim3(16, 32, 4), 256, 0, stream>>>(Eb, Evb, Rb, Wt, qb, kb, vt, Qpb);

  // 3) attention -> bf16 O (8-wave in-block j-split, shuffle remap)
  attn_s<<<512, 512, 0, stream>>>(qb, kb, vt, Qpb, cb, pb, Ob);

  // 4) output projection -> fp32 proj
  out_g<<<dim3(16, 32), 256, 0, stream>>>(Ob, Wt + 4 * (size_t)D_ * D_, proj);

  // 5) residual + LayerNorm
  ln_kernel<<<B_ * L_, 256, 0, stream>>>(Ev, proj, Wo_b, ln_g, ln_b, out);
}

// Round 10
// 223.653 us; speedup vs baseline: 1.2104x; 1.2104x over previous
//
#include <hip/hip_runtime.h>
#include <hip/hip_bf16.h>
#include <math.h>

#define B_ 2
#define L_ 1024
#define D_ 1024
#define H_ 16

typedef short short8 __attribute__((ext_vector_type(8)));
typedef short short4v __attribute__((ext_vector_type(4)));
typedef float f32x4  __attribute__((ext_vector_type(4)));

__device__ __forceinline__ short f2bf(float f) {
  unsigned u = __float_as_uint(f);
  u += 0x7fff + ((u >> 16) & 1);          // RNE
  return (short)(u >> 16);
}
__device__ __forceinline__ float bf2f(short s) {
  return __uint_as_float(((unsigned)(unsigned short)s) << 16);
}
// XOR-swizzled LDS index (shorts) for [rows][64] bf16 tiles (16B slots).
__device__ __forceinline__ int swz(int row, int slot) {
  return row * 64 + (((slot ^ row) & 7) << 3);
}
// P-tile XOR key (wave-private P buffer bank spread)
__device__ __forceinline__ int pkey(int row) {
  return (row & 7) ^ ((row & 8) >> 2);
}
// global -> LDS direct (16B/lane; LDS dest = wave-uniform base + lane*16)
__device__ __forceinline__ void glds16(const void* g, void* l) {
  __builtin_amdgcn_global_load_lds((const __attribute__((address_space(1))) void*)g,
                                   (__attribute__((address_space(3))) void*)l, 16, 0, 0);
}

// ---------------------------------------------------------------------------
// prep: (a) cast E,Ev,R -> bf16 contiguous; (b) transpose+cast 5 weights.
// ---------------------------------------------------------------------------
__global__ __launch_bounds__(256) void prep(
    const float* __restrict__ E, const float* __restrict__ Ev,
    const float* __restrict__ R,
    const float* __restrict__ W0, const float* __restrict__ W1,
    const float* __restrict__ W2, const float* __restrict__ W3,
    const float* __restrict__ W4,
    short* __restrict__ act, short* __restrict__ Wt) {
  __shared__ short t[64][65];
  const int tid = threadIdx.x;
  int bid = blockIdx.x;
  if (bid < 2560) {
    size_t i8 = ((size_t)bid * 256 + tid) * 8;
    const float* src; size_t off;
    if (i8 < 2097152)      { src = E;  off = i8; }
    else if (i8 < 4194304) { src = Ev; off = i8 - 2097152; }
    else                   { src = R;  off = i8 - 4194304; }
    float4 a = *(const float4*)&src[off];
    float4 b = *(const float4*)&src[off + 4];
    short8 v;
    v[0] = f2bf(a.x); v[1] = f2bf(a.y); v[2] = f2bf(a.z); v[3] = f2bf(a.w);
    v[4] = f2bf(b.x); v[5] = f2bf(b.y); v[6] = f2bf(b.z); v[7] = f2bf(b.w);
    *(short8*)&act[i8] = v;
    return;
  }
  bid -= 2560;
  const int z = bid >> 8, rem = bid & 255;
  const int by = rem >> 4, bx = rem & 15;
  const float* W = (z == 0) ? W0 : (z == 1) ? W1 : (z == 2) ? W2 : (z == 3) ? W3 : W4;
  short* Wtz = Wt + (size_t)z * D_ * D_;
  const int r0 = by * 64, c0 = bx * 64;
  #pragma unroll
  for (int i = 0; i < 4; ++i) {
    int idx = tid + i * 256;
    int r = idx >> 4, c4 = (idx & 15) * 4;
    float4 v = *(const float4*)&W[(size_t)(r0 + r) * D_ + c0 + c4];
    t[c4 + 0][r] = f2bf(v.x); t[c4 + 1][r] = f2bf(v.y);
    t[c4 + 2][r] = f2bf(v.z); t[c4 + 3][r] = f2bf(v.w);
  }
  __syncthreads();
  #pragma unroll
  for (int i = 0; i < 2; ++i) {
    int idx = tid + i * 256;
    int rr = idx >> 3, cc = (idx & 7) * 8;
    short8 o;
    #pragma unroll
    for (int e = 0; e < 8; ++e) o[e] = t[rr][cc + e];
    *(short8*)&Wtz[(size_t)(c0 + rr) * D_ + r0 + cc] = o;
  }
}

// ---------------------------------------------------------------------------
// Double-buffered bf16 MFMA GEMM (R7 config: NF=2, 32KB LDS, 5 blocks/CU).
// C = A[M,1024] @ Bt[1024,1024]^T. Tile 64x64, BK=64, 4 waves. STAGE(t+1)
// before COMPUTE(t); 1 barrier/K-step. OUT: 0 bf16, 1 f32, 2 bf16 per-head
// transposed vt[((b*16+h)*64+d)*1024 + j].
// ---------------------------------------------------------------------------
template<int NF, int OUT>
__device__ __forceinline__ void mm_db(const short* __restrict__ A,
                                      const short* __restrict__ Bt,
                                      void* __restrict__ Cp,
                                      int bx, int by) {
  __shared__ short As0[4096], As1[4096];
  __shared__ short Bs0[NF * 2048], Bs1[NF * 2048];
  const int tid = threadIdx.x;
  const int l = tid & 63, w = tid >> 6;
  const int row0 = by * 64, col0 = bx * (NF * 32);
  const int wm = (w >> 1) * 32, wn = (w & 1) * (NF * 16);
  const int lr = l >> 3;
  const int lc = ((l & 7) ^ lr) * 8;     // inverse-swizzled source slot
  const f32x4 fz = {0.f, 0.f, 0.f, 0.f};

  f32x4 acc[2][NF];
  #pragma unroll
  for (int i = 0; i < 2; ++i)
    #pragma unroll
    for (int j = 0; j < NF; ++j) acc[i][j] = fz;

  auto STAGE = [&](short* AsD, short* BsD, int k0) {
    #pragma unroll
    for (int c = 0; c < 2; ++c) {
      int ch = w * 2 + c;
      glds16(&A[(size_t)(row0 + ch * 8 + lr) * 1024 + k0 + lc], &AsD[ch * 512]);
    }
    #pragma unroll
    for (int c = 0; c < NF; ++c) {
      int ch = w * NF + c;
      glds16(&Bt[(size_t)(col0 + ch * 8 + lr) * 1024 + k0 + lc], &BsD[ch * 512]);
    }
  };
  auto COMP = [&](const short* AsS, const short* BsS) {
    #pragma unroll
    for (int kf = 0; kf < 2; ++kf) {
      const int slot = kf * 4 + (l >> 4);
      short8 a[2], bfr[NF];
      #pragma unroll
      for (int mf = 0; mf < 2; ++mf)
        a[mf] = *(const short8*)&AsS[swz(wm + mf * 16 + (l & 15), slot)];
      #pragma unroll
      for (int nf = 0; nf < NF; ++nf)
        bfr[nf] = *(const short8*)&BsS[swz(wn + nf * 16 + (l & 15), slot)];
      #pragma unroll
      for (int mf = 0; mf < 2; ++mf)
        #pragma unroll
        for (int nf = 0; nf < NF; ++nf)
          acc[mf][nf] = __builtin_amdgcn_mfma_f32_16x16x32_bf16(a[mf], bfr[nf], acc[mf][nf], 0, 0, 0);
    }
  };

  STAGE(As0, Bs0, 0);
  __syncthreads();
  for (int t = 0; t < 16; t += 2) {
    if (t + 1 < 16) STAGE(As1, Bs1, (t + 1) * 64);
    COMP(As0, Bs0);
    __syncthreads();
    if (t + 2 < 16) STAGE(As0, Bs0, (t + 2) * 64);
    COMP(As1, Bs1);
    __syncthreads();
  }

  #pragma unroll
  for (int mf = 0; mf < 2; ++mf)
    #pragma unroll
    for (int nf = 0; nf < NF; ++nf) {
      if (OUT == 2) {
        int tok = row0 + wm + mf * 16 + (l >> 4) * 4;
        int col = col0 + wn + nf * 16 + (l & 15);
        int bb = tok >> 10, j = tok & 1023;
        int h = col >> 6, d = col & 63;
        short4v o;
        #pragma unroll
        for (int r = 0; r < 4; ++r) o[r] = f2bf(acc[mf][nf][r]);
        *(short4v*)&((short*)Cp)[((size_t)((bb * H_ + h) * 64 + d)) * 1024 + j] = o;
      } else {
        #pragma unroll
        for (int r = 0; r < 4; ++r) {
          int row = row0 + wm + mf * 16 + (l >> 4) * 4 + r;
          int col = col0 + wn + nf * 16 + (l & 15);
          if (OUT == 1) ((float*)Cp)[(size_t)row * 1024 + col] = acc[mf][nf][r];
          else          ((short*)Cp)[(size_t)row * 1024 + col] = f2bf(acc[mf][nf][r]);
        }
      }
    }
}

// z=0: q=Eb@Wq ; z=1: k=Evb@Wke ; z=2: vt=(Evb@Wv)^T ; z=3: Qp=Rb@Wkr.
__global__ __launch_bounds__(256) void proj_g(
    const short* __restrict__ Eb, const short* __restrict__ Evb,
    const short* __restrict__ Rb, const short* __restrict__ Wt,
    short* __restrict__ qb, short* __restrict__ kb,
    short* __restrict__ vt, short* __restrict__ Qpb) {
  const int z = blockIdx.z;
  const size_t MM = (size_t)D_ * D_;
  const short* A; const short* Bt; short* C; int M;
  if (z == 0)      { A = Eb;  Bt = Wt;          C = qb;  M = B_ * L_; }
  else if (z == 1) { A = Evb; Bt = Wt + MM;     C = kb;  M = B_ * L_; }
  else if (z == 2) { A = Evb; Bt = Wt + 3 * MM; C = vt;  M = B_ * L_; }
  else             { A = Rb;  Bt = Wt + 2 * MM; C = Qpb; M = L_;      }
  if ((int)blockIdx.y * 64 >= M) return;
  if (z == 2) mm_db<2, 2>(A, Bt, C, blockIdx.x, blockIdx.y);
  else        mm_db<2, 0>(A, Bt, C, blockIdx.x, blockIdx.y);
}

__global__ __launch_bounds__(256) void out_g(
    const short* __restrict__ Ob, const short* __restrict__ Wot,
    float* __restrict__ proj) {
  mm_db<2, 1>(Ob, Wot, proj, blockIdx.x, blockIdx.y);
}

// ---------------------------------------------------------------------------
// MFMA attention, 8 waves, in-block j-split (R9 structure, spill-fixed:
// window fragments loaded direct from global at use -> ~40 fewer VGPRs,
// fits the (512,4) 128-reg budget; 2 blocks/CU = 16 waves/CU).
// Waves 0-3 even j-tiles, waves 4-7 odd, private (m,l,O); flash-merge via
// LDS at the end. K/V^T pair-staged dbuf via glds16. Positional diagonal
// shift via in-register __shfl remap. S = (q+cb).k + (q+pb).Qp[m].
// ---------------------------------------------------------------------------
__global__ __launch_bounds__(512, 4) void attn_s(
    const short* __restrict__ qb, const short* __restrict__ kb,
    const short* __restrict__ vt, const short* __restrict__ Qpb,
    const float* __restrict__ cb, const float* __restrict__ pb,
    short* __restrict__ Ob) {
  __shared__ short k_s[2][2][4096];   // [buf][pairIdx][64x64]
  __shared__ short v_s[2][2][4096];
  __shared__ short p_s[8][1024];      // per-wave P[16][64]

  const int tid = threadIdx.x;
  const int l = tid & 63, w = tid >> 6;   // w 0..7
  const int grp = w >> 2, wl = w & 3;
  const int hl = blockIdx.x & 31;         // (b,h) fastest -> XCD L2 locality
  const int it = blockIdx.x >> 5;         // 0..15
  const int b = hl >> 4, hh = hl & 15;
  const int i0 = it * 64;
  const int i0w = i0 + wl * 16;           // this wave's first q row
  const f32x4 fz = {0.f, 0.f, 0.f, 0.f};

  const int lr = l >> 3;
  const int lc = ((l & 7) ^ lr) * 8;      // inverse-swizzled source slot

  // ---- A-fragments with folded biases ----
  short8 aqc[2], aqp[2];
  {
    const size_t qoff = (size_t)(b * L_ + i0w + (l & 15)) * D_ + hh * 64 + (l >> 4) * 8;
    #pragma unroll
    for (int kf = 0; kf < 2; ++kf) {
      short8 qv = *(const short8*)&qb[qoff + kf * 32];
      const float* cbp = &cb[hh * 64 + kf * 32 + (l >> 4) * 8];
      const float* pbp = &pb[hh * 64 + kf * 32 + (l >> 4) * 8];
      #pragma unroll
      for (int e = 0; e < 8; ++e) {
        float q = bf2f(qv[e]);
        aqc[kf][e] = f2bf(q + cbp[e]);
        aqp[kf][e] = f2bf(q + pbp[e]);
      }
    }
  }

  const short* kbase  = &kb[(size_t)(b * L_) * D_ + hh * 64];
  const short* vtbase = &vt[(size_t)((b * H_ + hh) * 64) * 1024];
  const short* wbase  = &Qpb[hh * 64 + (l >> 4) * 8];

  // pair staging: wave w stages chunk w (8 rows) of each {k,v}x{tile0,tile1}
  auto STAGE = [&](int buf, int rnd) {
    #pragma unroll
    for (int tp = 0; tp < 2; ++tp) {
      const int j0 = (2 * rnd + tp) * 64;
      glds16(&kbase[(size_t)(j0 + w * 8 + lr) * D_ + lc], &k_s[buf][tp][w * 512]);
      glds16(&vtbase[(size_t)(w * 8 + lr) * 1024 + j0 + lc], &v_s[buf][tp][w * 512]);
    }
  };

  STAGE(0, 0);
  __syncthreads();

  float mrow[4], lrow[4];
  f32x4 oacc[4];
  #pragma unroll
  for (int r = 0; r < 4; ++r) { mrow[r] = -3.0e38f; lrow[r] = 0.f; }
  #pragma unroll
  for (int nf = 0; nf < 4; ++nf) oacc[nf] = fz;

  for (int rnd = 0; rnd < 8; ++rnd) {
    const int jt = 2 * rnd + grp;
    const int dth = i0w - jt * 64;        // j<=i  <=>  rj <= ris + dth
    const bool pos = (dth >= -15);
    const short* kS = k_s[rnd & 1][grp];
    const short* vS = v_s[rnd & 1][grp];

    if (rnd < 7) STAGE((rnd + 1) & 1, rnd + 1);   // flies under compute

    // ---- QK^T ----
    f32x4 sac[4];
    #pragma unroll
    for (int nf = 0; nf < 4; ++nf) sac[nf] = fz;
    __builtin_amdgcn_s_setprio(1);
    #pragma unroll
    for (int kf = 0; kf < 2; ++kf) {
      const int slot = kf * 4 + (l >> 4);
      #pragma unroll
      for (int nf = 0; nf < 4; ++nf) {
        short8 bk = *(const short8*)&kS[swz(nf * 16 + (l & 15), slot)];
        sac[nf] = __builtin_amdgcn_mfma_f32_16x16x32_bf16(aqc[kf], bk, sac[nf], 0, 0, 0);
      }
    }
    __builtin_amdgcn_s_setprio(0);

    // ---- positional GEMM: window B-frags direct from global (L2) ----
    f32x4 pacc[5];
    if (pos) {
      const int mb = L_ - 16 - dth;
      #pragma unroll
      for (int u = 0; u < 5; ++u) pacc[u] = fz;
      __builtin_amdgcn_s_setprio(1);
      #pragma unroll
      for (int kf = 0; kf < 2; ++kf)
        #pragma unroll
        for (int u = 0; u < 5; ++u) {
          int m = mb + u * 16 + (l & 15);
          m = (m < L_) ? m : (L_ - 1);    // clamped rows masked in remap
          short8 bwv = *(const short8*)&wbase[(size_t)m * D_ + kf * 32];
          pacc[u] = __builtin_amdgcn_mfma_f32_16x16x32_bf16(aqp[kf], bwv, pacc[u], 0, 0, 0);
        }
      __builtin_amdgcn_s_setprio(0);

      // in-register diagonal remap: S[ris][rj] += W[ris][(15-ris)+rj]
      // Shift (15-ris) uniform per 16-lane row group.
      const int c = l & 15;
      #pragma unroll
      for (int r = 0; r < 4; ++r) {
        const int ris = (l >> 4) * 4 + r;
        const int t = (15 - ris) + c;            // 0..30
        const int sl = (l & 48) | (t & 15);      // absolute source lane
        const bool hi = t >= 16;
        float shf[5];
        #pragma unroll
        for (int u = 0; u < 5; ++u) shf[u] = __shfl(pacc[u][r], sl, 64);
        #pragma unroll
        for (int nf = 0; nf < 4; ++nf) {
          int rj = nf * 16 + c;
          if (rj <= ris + dth) sac[nf][r] += hi ? shf[nf + 1] : shf[nf];
        }
      }
    }

    // ---- online softmax (16-lane row groups) ----
    #pragma unroll
    for (int r = 0; r < 4; ++r) {
      float mx = fmaxf(fmaxf(sac[0][r], sac[1][r]), fmaxf(sac[2][r], sac[3][r]));
      #pragma unroll
      for (int off = 1; off < 16; off <<= 1)
        mx = fmaxf(mx, __shfl_xor(mx, off, 64));
      float mn = fmaxf(mrow[r], mx);
      float sc = __expf(mrow[r] - mn);
      mrow[r] = mn;
      float ls = 0.f;
      #pragma unroll
      for (int nf = 0; nf < 4; ++nf) {
        float p = __expf(sac[nf][r] - mn);
        sac[nf][r] = p;
        ls += p;
      }
      #pragma unroll
      for (int off = 1; off < 16; off <<= 1)
        ls += __shfl_xor(ls, off, 64);
      lrow[r] = lrow[r] * sc + ls;
      #pragma unroll
      for (int nf = 0; nf < 4; ++nf) oacc[nf][r] *= sc;
    }

    // ---- P -> bf16, wave-private LDS ----
    #pragma unroll
    for (int nf = 0; nf < 4; ++nf)
      #pragma unroll
      for (int r = 0; r < 4; ++r) {
        int row = (l >> 4) * 4 + r;
        int col = nf * 16 + (l & 15);
        p_s[w][row * 64 + (((col >> 3) ^ pkey(row)) << 3) + (col & 7)] = f2bf(sac[nf][r]);
      }

    // ---- PV from staged V^T ----
    __builtin_amdgcn_s_setprio(1);
    #pragma unroll
    for (int kf = 0; kf < 2; ++kf) {
      int prow = l & 15;
      short8 ap = *(const short8*)&p_s[w][prow * 64 + (((kf * 4 + (l >> 4)) ^ pkey(prow)) << 3)];
      #pragma unroll
      for (int nf = 0; nf < 4; ++nf) {
        short8 bv = *(const short8*)&vS[swz(nf * 16 + (l & 15), kf * 4 + (l >> 4))];
        oacc[nf] = __builtin_amdgcn_mfma_f32_16x16x32_bf16(ap, bv, oacc[nf], 0, 0, 0);
      }
    }
    __builtin_amdgcn_s_setprio(0);

    __syncthreads();   // next-round stage complete; buffers rotate
  }

  // ---- merge the two j-streams (flash combine) via LDS ----
  float* mO = (float*)&k_s[0][0][0];      // [4 waves][16 rows][64 cols] f32
  float* mM = (float*)&v_s[0][0][0];      // [4][16]
  float* mL = mM + 64;
  if (grp == 1) {
    #pragma unroll
    for (int r = 0; r < 4; ++r) {
      int ris = (l >> 4) * 4 + r;
      #pragma unroll
      for (int nf = 0; nf < 4; ++nf)
        mO[(wl * 16 + ris) * 64 + nf * 16 + (l & 15)] = oacc[nf][r];
      if ((l & 15) == 0) { mM[wl * 16 + ris] = mrow[r]; mL[wl * 16 + ris] = lrow[r]; }
    }
  }
  __syncthreads();
  if (grp == 0) {
    #pragma unroll
    for (int r = 0; r < 4; ++r) {
      int ris = (l >> 4) * 4 + r;
      float mB = mM[wl * 16 + ris], lB = mL[wl * 16 + ris];
      float m = fmaxf(mrow[r], mB);
      float eA = __expf(mrow[r] - m), eB = __expf(mB - m);
      float inv = 1.f / (lrow[r] * eA + lB * eB);
      int row = i0w + ris;
      #pragma unroll
      for (int nf = 0; nf < 4; ++nf) {
        float vB = mO[(wl * 16 + ris) * 64 + nf * 16 + (l & 15)];
        int col = hh * 64 + nf * 16 + (l & 15);
        Ob[(size_t)(b * L_ + row) * D_ + col] = f2bf((oacc[nf][r] * eA + vB * eB) * inv);
      }
    }
  }
}

// ---------------------------------------------------------------------------
// res = Ev + proj + Wo_b; LayerNorm * g + b. One block per row.
// ---------------------------------------------------------------------------
__global__ __launch_bounds__(256) void ln_kernel(
    const float* __restrict__ Ev, const float* __restrict__ proj,
    const float* __restrict__ Wo_b, const float* __restrict__ g,
    const float* __restrict__ beta, float* __restrict__ out) {
  const int row = blockIdx.x;
  __shared__ float red[8];
  const int tid = threadIdx.x;
  const int d = tid * 4;

  float4 e  = *(const float4*)&Ev[(size_t)row * D_ + d];
  float4 p  = *(const float4*)&proj[(size_t)row * D_ + d];
  float4 wb = *(const float4*)&Wo_b[d];
  float4 rr = { e.x + p.x + wb.x, e.y + p.y + wb.y,
                e.z + p.z + wb.z, e.w + p.w + wb.w };
  float sum = rr.x + rr.y + rr.z + rr.w;
  float sq  = rr.x * rr.x + rr.y * rr.y + rr.z * rr.z + rr.w * rr.w;

  #pragma unroll
  for (int off = 1; off < 64; off <<= 1) {
    sum += __shfl_xor(sum, off, 64);
    sq  += __shfl_xor(sq,  off, 64);
  }
  const int wid = tid >> 6;
  if ((tid & 63) == 0) { red[wid * 2] = sum; red[wid * 2 + 1] = sq; }
  __syncthreads();
  sum = red[0] + red[2] + red[4] + red[6];
  sq  = red[1] + red[3] + red[5] + red[7];

  const float mu   = sum * (1.f / (float)D_);
  const float var  = sq * (1.f / (float)D_) - mu * mu;
  const float rstd = rsqrtf(var + 1e-5f);

  float4 gg = *(const float4*)&g[d];
  float4 bb = *(const float4*)&beta[d];
  float4 o = { (rr.x - mu) * rstd * gg.x + bb.x,
               (rr.y - mu) * rstd * gg.y + bb.y,
               (rr.z - mu) * rstd * gg.z + bb.z,
               (rr.w - mu) * rstd * gg.w + bb.w };
  *(float4*)&out[(size_t)row * D_ + d] = o;
}

// ---------------------------------------------------------------------------
extern "C" void kernel_launch(void* const* d_in, const int* in_sizes, int n_in,
                              void* d_out, int out_size, void* d_ws, size_t ws_size,
                              hipStream_t stream) {
  const float* E    = (const float*)d_in[0];
  const float* Ev   = (const float*)d_in[1];
  const float* R    = (const float*)d_in[2];
  const float* Wq   = (const float*)d_in[3];
  const float* Wke  = (const float*)d_in[4];
  const float* Wkr  = (const float*)d_in[5];
  const float* Wv   = (const float*)d_in[6];
  const float* cb   = (const float*)d_in[7];
  const float* pb   = (const float*)d_in[8];
  const float* Wo_w = (const float*)d_in[9];
  const float* Wo_b = (const float*)d_in[10];
  const float* ln_g = (const float*)d_in[11];
  const float* ln_b = (const float*)d_in[12];
  float* out = (float*)d_out;

  // ws (shorts): Eb 2M | Evb 2M | Rb 1M | qb 2M | kb 2M | vt 2M | Qpb 1M |
  // Wt 5M | Ob 2M = 19M shorts = 38MB. proj fp32 overlays Eb+Evb.
  short* ws   = (short*)d_ws;
  short* Eb   = ws;
  short* Evb  = ws + 2097152;
  short* Rb   = ws + 4194304;
  short* qb   = ws + 5242880;
  short* kb   = ws + 7340032;
  short* vt   = ws + 9437184;
  short* Qpb  = ws + 11534336;
  short* Wt   = ws + 12582912;
  short* Ob   = ws + 17825792;
  float* proj = (float*)Eb;

  // 1) prep: cast activations + transpose/cast weights
  prep<<<3840, 256, 0, stream>>>(E, Ev, R, Wq, Wke, Wkr, Wv, Wo_w, Eb, Wt);

  // 2) projections -> bf16 q, k, vt(transposed), Qp  (NF=2 dbuf config)
  proj_g<<<dim3(16, 32, 4), 256, 0, stream>>>(Eb, Evb, Rb, Wt, qb, kb, vt, Qpb);

  // 3) attention -> bf16 O (8-wave j-split, direct window loads, no spill)
  attn_s<<<512, 512, 0, stream>>>(qb, kb, vt, Qpb, cb, pb, Ob);

  // 4) output projection -> fp32 proj
  out_g<<<dim3(16, 32), 256, 0, stream>>>(Ob, Wt + 4 * (size_t)D_ * D_, proj);

  // 5) residual + LayerNorm
  ln_kernel<<<B_ * L_, 256, 0, stream>>>(Ev, proj, Wo_b, ln_g, ln_b, out);
}